// Round 1
// baseline (483.286 us; speedup 1.0000x reference)
//
#include <hip/hip_runtime.h>

typedef __bf16 bf16x8 __attribute__((ext_vector_type(8)));
typedef float floatx4 __attribute__((ext_vector_type(4)));
typedef unsigned short ushort_t;
typedef ushort_t ushortx4 __attribute__((ext_vector_type(4)));
typedef float floatx4v __attribute__((ext_vector_type(4)));

typedef __attribute__((address_space(1))) void gvoid;
typedef __attribute__((address_space(3))) void svoid;

#define MFMA16(a, b, c) __builtin_amdgcn_mfma_f32_16x16x32_bf16(a, b, c, 0, 0, 0)

__device__ __forceinline__ ushort_t f2bf(float f) {
  unsigned u = __builtin_bit_cast(unsigned, f);
  u += 0x7fffu + ((u >> 16) & 1u);
  return (ushort_t)(u >> 16);
}

__device__ __forceinline__ void gld16(const ushort_t* g, ushort_t* l) {
  __builtin_amdgcn_global_load_lds((gvoid*)(g), (svoid*)(l), 16, 0, 0);
}

// ---------------------------------------------------------------- cast x -> bf16
__global__ __launch_bounds__(256) void k_cast_x(const floatx4v* __restrict__ in,
                                                ushortx4* __restrict__ out) {
  int i = blockIdx.x * 256 + threadIdx.x;
  floatx4v v = in[i];
  ushortx4 o;
  o[0] = f2bf(v[0]); o[1] = f2bf(v[1]); o[2] = f2bf(v[2]); o[3] = f2bf(v[3]);
  out[i] = o;
}

// ---------------------------------------------------------------- W (KxN fp32) -> W^T (Nx2048 bf16)
__global__ __launch_bounds__(256) void k_transpose_cast(const float* __restrict__ in,
                                                        ushort_t* __restrict__ out, int N) {
  __shared__ float tile[64][65];
  const int c0 = blockIdx.x * 64;  // N dim
  const int k0 = blockIdx.y * 64;  // K dim
  const int tx = threadIdx.x & 63;
  const int ty = threadIdx.x >> 6;
#pragma unroll
  for (int i = 0; i < 16; i++) {
    int row = i * 4 + ty;
    tile[tx][row] = in[(k0 + row) * N + c0 + tx];
  }
  __syncthreads();
#pragma unroll
  for (int i = 0; i < 16; i++) {
    int nr = i * 4 + ty;
    out[(c0 + nr) * 2048 + k0 + tx] = f2bf(tile[nr][tx]);
  }
}

// ---------------------------------------------------------------- fused QKV GEMM + RoPE epilogue
// A: x_bf16 (4096 x 2048), Bt: WqkvT (3072 x 2048).
// Q cols [0,2048): rope + scale -> Qh (B,H,T,128)
// K cols [2048,2560): rope -> Kh (B,Hkv,T,128)
// V cols [2560,3072): -> Vt (B,Hkv,128,T)  (transposed)
__global__ __launch_bounds__(256) void k_gemm_qkv(const ushort_t* __restrict__ A,
                                                  const ushort_t* __restrict__ Bt,
                                                  ushort_t* __restrict__ Qh,
                                                  ushort_t* __restrict__ Kh,
                                                  ushort_t* __restrict__ Vt) {
  __shared__ __align__(16) ushort_t As[4096];
  __shared__ __align__(16) ushort_t Bs[4096];
  const int t = threadIdx.x;
  const int w = t >> 6;
  const int lane = t & 63;
  const int r = lane & 15;
  const int q = lane >> 4;
  const int m0 = blockIdx.y * 128;
  const int n0 = blockIdx.x * 128;

  const int srow = t >> 2;
  const int gc = (t & 3) ^ ((t >> 3) & 3);          // swizzled global chunk
  const int a_g0 = (m0 + srow) * 2048 + gc * 8;
  const int b_g0 = (n0 + srow) * 2048 + gc * 8;
  ushort_t* as_l = As + t * 8;
  ushort_t* bs_l = Bs + t * 8;

  const int pos8 = (q ^ ((r >> 1) & 3)) * 8;        // swizzled read position
  const int a_off = (w * 32 + r) * 32 + pos8;
  const int b_off = r * 32 + pos8;

  const floatx4 fz = {0.f, 0.f, 0.f, 0.f};
  floatx4 acc[2][8];
#pragma unroll
  for (int i = 0; i < 2; i++)
#pragma unroll
    for (int jj = 0; jj < 8; jj++) acc[i][jj] = fz;

  for (int kt = 0; kt < 2048; kt += 32) {
    gld16(A + a_g0 + kt, as_l);
    gld16(A + a_g0 + 64 * 2048 + kt, as_l + 2048);
    gld16(Bt + b_g0 + kt, bs_l);
    gld16(Bt + b_g0 + 64 * 2048 + kt, bs_l + 2048);
    __syncthreads();
    bf16x8 af0 = *(const bf16x8*)(As + a_off);
    bf16x8 af1 = *(const bf16x8*)(As + a_off + 512);
    bf16x8 bfv[8];
#pragma unroll
    for (int ni = 0; ni < 8; ni++) bfv[ni] = *(const bf16x8*)(Bs + b_off + ni * 512);
#pragma unroll
    for (int ni = 0; ni < 8; ni++) {
      acc[0][ni] = MFMA16(af0, bfv[ni], acc[0][ni]);
      acc[1][ni] = MFMA16(af1, bfv[ni], acc[1][ni]);
    }
    __syncthreads();
  }

  const int bb = m0 >> 11;                 // batch index (tile never spans b)
  const int trow0 = (m0 & 2047) + w * 32;  // token base for this wave

  if (n0 < 2560) {
    const bool isQ = (n0 < 2048);
    const float scale = isQ ? 0.08838834764831845f : 1.0f;
    ushort_t* dst = isQ ? (Qh + ((bb * 16 + (n0 >> 7)) * 2048) * 128)
                        : (Kh + ((bb * 4 + ((n0 - 2048) >> 7)) * 2048) * 128);
#pragma unroll
    for (int mi = 0; mi < 2; mi++) {
#pragma unroll
      for (int ni = 0; ni < 4; ni++) {
        const int d = ni * 16 + r;
        const float invf = __expf(-0.14391156643f * (float)d);  // 10000^(-d/64)
#pragma unroll
        for (int reg = 0; reg < 4; reg++) {
          const int tt = trow0 + mi * 16 + q * 4 + reg;
          float sn, cs;
          sincosf((float)tt * invf, &sn, &cs);
          const float lo = acc[mi][ni][reg];
          const float hi = acc[mi][ni + 4][reg];
          dst[tt * 128 + d] = f2bf((lo * cs - hi * sn) * scale);
          dst[tt * 128 + d + 64] = f2bf((hi * cs + lo * sn) * scale);
        }
      }
    }
  } else {
    ushort_t* dst = Vt + ((bb * 4 + ((n0 - 2560) >> 7)) * 128) * 2048;
#pragma unroll
    for (int mi = 0; mi < 2; mi++) {
#pragma unroll
      for (int ni = 0; ni < 8; ni++) {
        const int d = ni * 16 + r;
        const int t0 = trow0 + mi * 16 + q * 4;
        ushortx4 pk;
#pragma unroll
        for (int reg = 0; reg < 4; reg++) pk[reg] = f2bf(acc[mi][ni][reg]);
        *(ushortx4*)(dst + d * 2048 + t0) = pk;
      }
    }
  }
}

// ---------------------------------------------------------------- flash attention (causal, GQA)
// grid: 512 blocks = (b,h) x 16 q-tiles of 128 rows; 256 threads (4 waves x 32 rows)
__global__ __launch_bounds__(256) void k_flash(const ushort_t* __restrict__ Qh,
                                               const ushort_t* __restrict__ Kh,
                                               const ushort_t* __restrict__ Vt,
                                               ushort_t* __restrict__ attn) {
  __shared__ __align__(16) ushort_t smem[32768];  // 64 KB
  ushort_t* Qs = smem;           // 128x128
  ushort_t* Ks = smem + 16384;   // 64x128 (aliased as Ps: 128x64 after mid-barrier)
  ushort_t* Vs = smem + 24576;   // 128x64 (Vt tile: rows=d, cols=kv)

  const int t = threadIdx.x;
  const int w = t >> 6;
  const int lane = t & 63;
  const int r = lane & 15;
  const int q = lane >> 4;
  const int rx = r & 7;

  const int bh = blockIdx.x >> 4;
  const int qt = blockIdx.x & 15;
  const int b = bh >> 4;
  const int h = bh & 15;
  const int hkv = h >> 2;

  const ushort_t* Qg = Qh + (bh * 2048 + qt * 128) * 128;
  const ushort_t* Kg = Kh + ((b * 4 + hkv) * 2048) * 128;
  const ushort_t* Vg = Vt + ((b * 4 + hkv) * 128) * 2048;

  // stage Q (8 x 4KB issues); first __syncthreads drains vmcnt
  {
    const int row = t >> 4;
    const int gcq = (t & 15) ^ ((t >> 4) & 7);
#pragma unroll
    for (int i = 0; i < 8; i++)
      gld16(Qg + (i * 16 + row) * 128 + gcq * 8, Qs + i * 2048 + t * 8);
  }

  const floatx4 fz = {0.f, 0.f, 0.f, 0.f};
  floatx4 acc_o[2][8];
#pragma unroll
  for (int i = 0; i < 2; i++)
#pragma unroll
    for (int jj = 0; jj < 8; jj++) acc_o[i][jj] = fz;
  float m_run[2][4], l_run[2][4];
#pragma unroll
  for (int i = 0; i < 2; i++)
#pragma unroll
    for (int jj = 0; jj < 4; jj++) { m_run[i][jj] = -1e30f; l_run[i][jj] = 0.f; }

  const int jmax = 2 * qt + 2;
  const int krow = t >> 4;
  const int gck = (t & 15) ^ ((t >> 4) & 7);
  const int vrow = t >> 3;
  const int gcv = (t & 7) ^ ((t >> 3) & 7);

  floatx4 s_acc[2][4];

  for (int j = 0; j < jmax; j++) {
    __syncthreads();  // prev PV done with Vs/Ps (and Q staged, iter 0)
#pragma unroll
    for (int i = 0; i < 4; i++)
      gld16(Kg + (j * 64 + i * 16 + krow) * 128 + gck * 8, Ks + i * 2048 + t * 8);
#pragma unroll
    for (int i = 0; i < 4; i++)
      gld16(Vg + (i * 32 + vrow) * 2048 + j * 64 + gcv * 8, Vs + i * 2048 + t * 8);
    __syncthreads();

    const bool full_mask = (j == jmax - 1) && (w < 2);  // upper diag half-tile: all masked
    if (!full_mask) {
#pragma unroll
      for (int mi = 0; mi < 2; mi++)
#pragma unroll
        for (int ni = 0; ni < 4; ni++) s_acc[mi][ni] = fz;
#pragma unroll
      for (int ks = 0; ks < 4; ks++) {
        const int pp = ((ks * 4 + q) ^ rx) * 8;
        bf16x8 a0 = *(const bf16x8*)(Qs + (w * 32 + r) * 128 + pp);
        bf16x8 a1 = *(const bf16x8*)(Qs + (w * 32 + 16 + r) * 128 + pp);
#pragma unroll
        for (int ni = 0; ni < 4; ni++) {
          bf16x8 bk = *(const bf16x8*)(Ks + (ni * 16 + r) * 128 + pp);
          s_acc[0][ni] = MFMA16(a0, bk, s_acc[0][ni]);
          s_acc[1][ni] = MFMA16(a1, bk, s_acc[1][ni]);
        }
      }
      // causal mask (only the two diagonal half-tiles need it)
      if ((j == 2 * qt && w < 2) || (j == jmax - 1 && w >= 2)) {
#pragma unroll
        for (int mi = 0; mi < 2; mi++)
#pragma unroll
          for (int ni = 0; ni < 4; ni++)
#pragma unroll
            for (int reg = 0; reg < 4; reg++) {
              const int row_g = qt * 128 + w * 32 + mi * 16 + q * 4 + reg;
              const int col_g = j * 64 + ni * 16 + r;
              if (col_g > row_g) s_acc[mi][ni][reg] = -1e30f;
            }
      }
      // online softmax (rows are wave-exclusive; 16-lane butterfly)
      float alpha[2][4];
#pragma unroll
      for (int mi = 0; mi < 2; mi++)
#pragma unroll
        for (int reg = 0; reg < 4; reg++) {
          float mx = fmaxf(fmaxf(s_acc[mi][0][reg], s_acc[mi][1][reg]),
                           fmaxf(s_acc[mi][2][reg], s_acc[mi][3][reg]));
          mx = fmaxf(mx, __shfl_xor(mx, 1));
          mx = fmaxf(mx, __shfl_xor(mx, 2));
          mx = fmaxf(mx, __shfl_xor(mx, 4));
          mx = fmaxf(mx, __shfl_xor(mx, 8));
          const float mn = fmaxf(m_run[mi][reg], mx);
          alpha[mi][reg] = __expf(m_run[mi][reg] - mn);
          m_run[mi][reg] = mn;
        }
#pragma unroll
      for (int mi = 0; mi < 2; mi++)
#pragma unroll
        for (int ni = 0; ni < 4; ni++)
#pragma unroll
          for (int reg = 0; reg < 4; reg++)
            s_acc[mi][ni][reg] = __expf(s_acc[mi][ni][reg] - m_run[mi][reg]);
#pragma unroll
      for (int mi = 0; mi < 2; mi++)
#pragma unroll
        for (int reg = 0; reg < 4; reg++) {
          float sm = s_acc[mi][0][reg] + s_acc[mi][1][reg] + s_acc[mi][2][reg] + s_acc[mi][3][reg];
          sm += __shfl_xor(sm, 1);
          sm += __shfl_xor(sm, 2);
          sm += __shfl_xor(sm, 4);
          sm += __shfl_xor(sm, 8);
          l_run[mi][reg] = l_run[mi][reg] * alpha[mi][reg] + sm;
        }
#pragma unroll
      for (int mi = 0; mi < 2; mi++)
#pragma unroll
        for (int nd = 0; nd < 8; nd++)
#pragma unroll
          for (int reg = 0; reg < 4; reg++) acc_o[mi][nd][reg] *= alpha[mi][reg];
    }
    __syncthreads();  // all waves done reading Ks before it becomes Ps
    if (!full_mask) {
      // P (bf16) -> Ps in A-operand-friendly swizzled layout (own rows only)
#pragma unroll
      for (int mi = 0; mi < 2; mi++)
#pragma unroll
        for (int ni = 0; ni < 4; ni++)
#pragma unroll
          for (int reg = 0; reg < 4; reg++) {
            const int row_l = w * 32 + mi * 16 + q * 4 + reg;
            const int col = ni * 16 + r;
            Ks[row_l * 64 + ((col >> 3) ^ (row_l & 7)) * 8 + (col & 7)] =
                f2bf(s_acc[mi][ni][reg]);
          }
      // O += P @ V  (same-wave DS ops are in order; no barrier needed)
#pragma unroll
      for (int ks = 0; ks < 2; ks++) {
        const int pp = ((ks * 4 + q) ^ rx) * 8;
        bf16x8 a0 = *(const bf16x8*)(Ks + (w * 32 + r) * 64 + pp);
        bf16x8 a1 = *(const bf16x8*)(Ks + (w * 32 + 16 + r) * 64 + pp);
#pragma unroll
        for (int nd = 0; nd < 8; nd++) {
          bf16x8 bv = *(const bf16x8*)(Vs + (nd * 16 + r) * 64 + pp);
          acc_o[0][nd] = MFMA16(a0, bv, acc_o[0][nd]);
          acc_o[1][nd] = MFMA16(a1, bv, acc_o[1][nd]);
        }
      }
    }
  }

  // epilogue: O /= l, write bf16 to attn (B*T, 2048) head-major cols
  ushort_t* dst = attn + (b * 2048 + qt * 128) * 2048 + h * 128;
#pragma unroll
  for (int mi = 0; mi < 2; mi++)
#pragma unroll
    for (int reg = 0; reg < 4; reg++) {
      const float inv = 1.0f / l_run[mi][reg];
      const int row_l = w * 32 + mi * 16 + q * 4 + reg;
#pragma unroll
      for (int nd = 0; nd < 8; nd++)
        dst[row_l * 2048 + nd * 16 + r] = f2bf(acc_o[mi][nd][reg] * inv);
    }
}

// ---------------------------------------------------------------- output projection GEMM
__global__ __launch_bounds__(256) void k_gemm_out(const ushort_t* __restrict__ A,
                                                  const ushort_t* __restrict__ Bt,
                                                  float* __restrict__ out) {
  __shared__ __align__(16) ushort_t As[4096];
  __shared__ __align__(16) ushort_t Bs[4096];
  const int t = threadIdx.x;
  const int w = t >> 6;
  const int lane = t & 63;
  const int r = lane & 15;
  const int q = lane >> 4;
  const int m0 = blockIdx.y * 128;
  const int n0 = blockIdx.x * 128;

  const int srow = t >> 2;
  const int gc = (t & 3) ^ ((t >> 3) & 3);
  const int a_g0 = (m0 + srow) * 2048 + gc * 8;
  const int b_g0 = (n0 + srow) * 2048 + gc * 8;
  ushort_t* as_l = As + t * 8;
  ushort_t* bs_l = Bs + t * 8;

  const int pos8 = (q ^ ((r >> 1) & 3)) * 8;
  const int a_off = (w * 32 + r) * 32 + pos8;
  const int b_off = r * 32 + pos8;

  const floatx4 fz = {0.f, 0.f, 0.f, 0.f};
  floatx4 acc[2][8];
#pragma unroll
  for (int i = 0; i < 2; i++)
#pragma unroll
    for (int jj = 0; jj < 8; jj++) acc[i][jj] = fz;

  for (int kt = 0; kt < 2048; kt += 32) {
    gld16(A + a_g0 + kt, as_l);
    gld16(A + a_g0 + 64 * 2048 + kt, as_l + 2048);
    gld16(Bt + b_g0 + kt, bs_l);
    gld16(Bt + b_g0 + 64 * 2048 + kt, bs_l + 2048);
    __syncthreads();
    bf16x8 af0 = *(const bf16x8*)(As + a_off);
    bf16x8 af1 = *(const bf16x8*)(As + a_off + 512);
    bf16x8 bfv[8];
#pragma unroll
    for (int ni = 0; ni < 8; ni++) bfv[ni] = *(const bf16x8*)(Bs + b_off + ni * 512);
#pragma unroll
    for (int ni = 0; ni < 8; ni++) {
      acc[0][ni] = MFMA16(af0, bfv[ni], acc[0][ni]);
      acc[1][ni] = MFMA16(af1, bfv[ni], acc[1][ni]);
    }
    __syncthreads();
  }

#pragma unroll
  for (int mi = 0; mi < 2; mi++)
#pragma unroll
    for (int ni = 0; ni < 8; ni++)
#pragma unroll
      for (int reg = 0; reg < 4; reg++)
        out[(m0 + w * 32 + mi * 16 + q * 4 + reg) * 2048 + n0 + ni * 16 + r] =
            acc[mi][ni][reg];
}

// ---------------------------------------------------------------- launch
extern "C" void kernel_launch(void* const* d_in, const int* in_sizes, int n_in,
                              void* d_out, int out_size, void* d_ws, size_t ws_size,
                              hipStream_t stream) {
  (void)in_sizes; (void)n_in; (void)out_size; (void)ws_size;
  const float* x  = (const float*)d_in[0];
  const float* Wq = (const float*)d_in[1];
  const float* Wk = (const float*)d_in[2];
  const float* Wv = (const float*)d_in[3];
  const float* Wo = (const float*)d_in[4];
  float* out = (float*)d_out;

  char* ws = (char*)d_ws;
  ushort_t* x_bf   = (ushort_t*)(ws);               // 4096x2048        16,777,216 B
  ushort_t* WqkvT  = (ushort_t*)(ws + 16777216);    // 3072x2048        12,582,912 B
  ushort_t* WoT    = (ushort_t*)(ws + 29360128);    // 2048x2048         8,388,608 B
  ushort_t* Qh     = (ushort_t*)(ws + 37748736);    // (B,16,2048,128)  16,777,216 B
  ushort_t* Kh     = (ushort_t*)(ws + 54525952);    // (B,4,2048,128)    4,194,304 B
  ushort_t* Vt     = (ushort_t*)(ws + 58720256);    // (B,4,128,2048)    4,194,304 B
  ushort_t* attn   = (ushort_t*)(ws + 62914560);    // 4096x2048        16,777,216 B

  k_cast_x<<<8192, 256, 0, stream>>>((const floatx4v*)x, (ushortx4*)x_bf);
  k_transpose_cast<<<dim3(32, 32), 256, 0, stream>>>(Wq, WqkvT, 2048);
  k_transpose_cast<<<dim3(8, 32), 256, 0, stream>>>(Wk, WqkvT + 2048 * 2048, 512);
  k_transpose_cast<<<dim3(8, 32), 256, 0, stream>>>(Wv, WqkvT + 2560 * 2048, 512);
  k_transpose_cast<<<dim3(32, 32), 256, 0, stream>>>(Wo, WoT, 2048);
  k_gemm_qkv<<<dim3(24, 32), 256, 0, stream>>>(x_bf, WqkvT, Qh, Kh, Vt);
  k_flash<<<512, 256, 0, stream>>>(Qh, Kh, Vt, attn);
  k_gemm_out<<<dim3(16, 32), 256, 0, stream>>>(attn, WoT, out);
}

// Round 2
// 384.638 us; speedup vs baseline: 1.2565x; 1.2565x over previous
//
#include <hip/hip_runtime.h>

typedef __bf16 bf16x8 __attribute__((ext_vector_type(8)));
typedef float floatx4 __attribute__((ext_vector_type(4)));
typedef unsigned short ushort_t;
typedef ushort_t ushortx4 __attribute__((ext_vector_type(4)));
typedef float floatx4v __attribute__((ext_vector_type(4)));

typedef __attribute__((address_space(1))) void gvoid;
typedef __attribute__((address_space(3))) void svoid;

#define MFMA16(a, b, c) __builtin_amdgcn_mfma_f32_16x16x32_bf16(a, b, c, 0, 0, 0)

__device__ __forceinline__ ushort_t f2bf(float f) {
  unsigned u = __builtin_bit_cast(unsigned, f);
  u += 0x7fffu + ((u >> 16) & 1u);
  return (ushort_t)(u >> 16);
}

__device__ __forceinline__ void gld16(const ushort_t* g, ushort_t* l) {
  __builtin_amdgcn_global_load_lds((gvoid*)(g), (svoid*)(l), 16, 0, 0);
}

// ---------------------------------------------------------------- cast x -> bf16
__global__ __launch_bounds__(256) void k_cast_x(const floatx4v* __restrict__ in,
                                                ushortx4* __restrict__ out) {
  int i = blockIdx.x * 256 + threadIdx.x;
  floatx4v v = in[i];
  ushortx4 o;
  o[0] = f2bf(v[0]); o[1] = f2bf(v[1]); o[2] = f2bf(v[2]); o[3] = f2bf(v[3]);
  out[i] = o;
}

// ---------------------------------------------------------------- W (KxN fp32) -> W^T (Nx2048 bf16)
__global__ __launch_bounds__(256) void k_transpose_cast(const float* __restrict__ in,
                                                        ushort_t* __restrict__ out, int N) {
  __shared__ float tile[64][65];
  const int c0 = blockIdx.x * 64;  // N dim
  const int k0 = blockIdx.y * 64;  // K dim
  const int tx = threadIdx.x & 63;
  const int ty = threadIdx.x >> 6;
#pragma unroll
  for (int i = 0; i < 16; i++) {
    int row = i * 4 + ty;
    tile[tx][row] = in[(k0 + row) * N + c0 + tx];
  }
  __syncthreads();
#pragma unroll
  for (int i = 0; i < 16; i++) {
    int nr = i * 4 + ty;
    out[(c0 + nr) * 2048 + k0 + tx] = f2bf(tile[nr][tx]);
  }
}

// ---------------------------------------------------------------- fused QKV GEMM + RoPE epilogue
// A: x_bf16 (4096 x 2048), Bt: WqkvT (3072 x 2048).
// Q cols [0,2048): rope + scale -> Qh (B,H,T,128)
// K cols [2048,2560): rope -> Kh (B,Hkv,T,128)
// V cols [2560,3072): -> Vt (B,Hkv,128,T)  (transposed)
__global__ __launch_bounds__(256) void k_gemm_qkv(const ushort_t* __restrict__ A,
                                                  const ushort_t* __restrict__ Bt,
                                                  ushort_t* __restrict__ Qh,
                                                  ushort_t* __restrict__ Kh,
                                                  ushort_t* __restrict__ Vt) {
  __shared__ __align__(16) ushort_t As[4096];
  __shared__ __align__(16) ushort_t Bs[4096];
  const int t = threadIdx.x;
  const int w = t >> 6;
  const int lane = t & 63;
  const int r = lane & 15;
  const int q = lane >> 4;
  const int m0 = blockIdx.y * 128;
  const int n0 = blockIdx.x * 128;

  const int srow = t >> 2;
  const int gc = (t & 3) ^ ((t >> 3) & 3);          // swizzled global chunk
  const int a_g0 = (m0 + srow) * 2048 + gc * 8;
  const int b_g0 = (n0 + srow) * 2048 + gc * 8;
  ushort_t* as_l = As + t * 8;
  ushort_t* bs_l = Bs + t * 8;

  const int pos8 = (q ^ ((r >> 1) & 3)) * 8;        // swizzled read position
  const int a_off = (w * 32 + r) * 32 + pos8;
  const int b_off = r * 32 + pos8;

  const floatx4 fz = {0.f, 0.f, 0.f, 0.f};
  floatx4 acc[2][8];
#pragma unroll
  for (int i = 0; i < 2; i++)
#pragma unroll
    for (int jj = 0; jj < 8; jj++) acc[i][jj] = fz;

  for (int kt = 0; kt < 2048; kt += 32) {
    gld16(A + a_g0 + kt, as_l);
    gld16(A + a_g0 + 64 * 2048 + kt, as_l + 2048);
    gld16(Bt + b_g0 + kt, bs_l);
    gld16(Bt + b_g0 + 64 * 2048 + kt, bs_l + 2048);
    __syncthreads();
    bf16x8 af0 = *(const bf16x8*)(As + a_off);
    bf16x8 af1 = *(const bf16x8*)(As + a_off + 512);
    bf16x8 bfv[8];
#pragma unroll
    for (int ni = 0; ni < 8; ni++) bfv[ni] = *(const bf16x8*)(Bs + b_off + ni * 512);
#pragma unroll
    for (int ni = 0; ni < 8; ni++) {
      acc[0][ni] = MFMA16(af0, bfv[ni], acc[0][ni]);
      acc[1][ni] = MFMA16(af1, bfv[ni], acc[1][ni]);
    }
    __syncthreads();
  }

  const int bb = m0 >> 11;                 // batch index (tile never spans b)
  const int trow0 = (m0 & 2047) + w * 32;  // token base for this wave

  if (n0 < 2560) {
    const bool isQ = (n0 < 2048);
    const float scale = isQ ? 0.08838834764831845f : 1.0f;
    ushort_t* dst = isQ ? (Qh + ((bb * 16 + (n0 >> 7)) * 2048) * 128)
                        : (Kh + ((bb * 4 + ((n0 - 2048) >> 7)) * 2048) * 128);
#pragma unroll
    for (int mi = 0; mi < 2; mi++) {
#pragma unroll
      for (int ni = 0; ni < 4; ni++) {
        const int d = ni * 16 + r;
        const float invf = __expf(-0.14391156643f * (float)d);  // 10000^(-d/64)
#pragma unroll
        for (int reg = 0; reg < 4; reg++) {
          const int tt = trow0 + mi * 16 + q * 4 + reg;
          float sn, cs;
          __sincosf((float)tt * invf, &sn, &cs);
          const float lo = acc[mi][ni][reg];
          const float hi = acc[mi][ni + 4][reg];
          dst[tt * 128 + d] = f2bf((lo * cs - hi * sn) * scale);
          dst[tt * 128 + d + 64] = f2bf((hi * cs + lo * sn) * scale);
        }
      }
    }
  } else {
    ushort_t* dst = Vt + ((bb * 4 + ((n0 - 2560) >> 7)) * 128) * 2048;
#pragma unroll
    for (int mi = 0; mi < 2; mi++) {
#pragma unroll
      for (int ni = 0; ni < 8; ni++) {
        const int d = ni * 16 + r;
        const int t0 = trow0 + mi * 16 + q * 4;
        ushortx4 pk;
#pragma unroll
        for (int reg = 0; reg < 4; reg++) pk[reg] = f2bf(acc[mi][ni][reg]);
        *(ushortx4*)(dst + d * 2048 + t0) = pk;
      }
    }
  }
}

// ---------------------------------------------------------------- flash attention (causal, GQA)
// grid: 512 blocks; qt remapped so block i and i+256 (same CU under round-robin
// dispatch, 2 blocks/CU) have complementary work: qt(i)+qt(i+256)=15.
__global__ __launch_bounds__(256) void k_flash(const ushort_t* __restrict__ Qh,
                                               const ushort_t* __restrict__ Kh,
                                               const ushort_t* __restrict__ Vt,
                                               ushort_t* __restrict__ attn) {
  __shared__ __align__(16) ushort_t smem[32768];  // 64 KB
  ushort_t* Qs = smem;           // 128x128
  ushort_t* Ks = smem + 16384;   // 64x128 (aliased as Ps: 128x64 after mid-barrier)
  ushort_t* Vs = smem + 24576;   // 128x64 (Vt tile: rows=d, cols=kv)

  const int t = threadIdx.x;
  const int w = t >> 6;
  const int lane = t & 63;
  const int r = lane & 15;
  const int q = lane >> 4;
  const int rx = r & 7;

  // work-balanced remap
  const int kk = blockIdx.x & 255;
  const int hi2 = blockIdx.x >> 8;
  const int bh = kk >> 3;
  const int ss = kk & 7;
  const int qt = hi2 ? (15 - ss) : ss;

  const int b = bh >> 4;
  const int h = bh & 15;
  const int hkv = h >> 2;

  const ushort_t* Qg = Qh + (bh * 2048 + qt * 128) * 128;
  const ushort_t* Kg = Kh + ((b * 4 + hkv) * 2048) * 128;
  const ushort_t* Vg = Vt + ((b * 4 + hkv) * 128) * 2048;

  // stage Q (8 x 4KB issues); drained at first K-barrier
  {
    const int row = t >> 4;
    const int gcq = (t & 15) ^ ((t >> 4) & 7);
#pragma unroll
    for (int i = 0; i < 8; i++)
      gld16(Qg + (i * 16 + row) * 128 + gcq * 8, Qs + i * 2048 + t * 8);
  }

  const floatx4 fz = {0.f, 0.f, 0.f, 0.f};
  floatx4 acc_o[2][8];
#pragma unroll
  for (int i = 0; i < 2; i++)
#pragma unroll
    for (int jj = 0; jj < 8; jj++) acc_o[i][jj] = fz;
  float m_run[2][4], l_run[2][4];
#pragma unroll
  for (int i = 0; i < 2; i++)
#pragma unroll
    for (int jj = 0; jj < 4; jj++) { m_run[i][jj] = -1e30f; l_run[i][jj] = 0.f; }

  const int jmax = 2 * qt + 2;
  const int krow = t >> 4;
  const int gck = (t & 15) ^ ((t >> 4) & 7);
  const int vrow = t >> 3;
  const int gcv = (t & 7) ^ ((t >> 3) & 7);

  floatx4 s_acc[2][4];

  for (int j = 0; j < jmax; j++) {
    __syncthreads();  // b1: prev PV done with Vs/Ps (and Q staged, iter 0)
#pragma unroll
    for (int i = 0; i < 4; i++)
      gld16(Kg + (j * 64 + i * 16 + krow) * 128 + gck * 8, Ks + i * 2048 + t * 8);
    __syncthreads();  // b2: drains K (and Q on iter 0)
    // issue V now: latency hides under the QK/softmax phase, drained at b3
#pragma unroll
    for (int i = 0; i < 4; i++)
      gld16(Vg + (i * 32 + vrow) * 2048 + j * 64 + gcv * 8, Vs + i * 2048 + t * 8);

    const bool full_mask = (j == jmax - 1) && (w < 2);  // upper diag half-tile: all masked
    if (!full_mask) {
#pragma unroll
      for (int mi = 0; mi < 2; mi++)
#pragma unroll
        for (int ni = 0; ni < 4; ni++) s_acc[mi][ni] = fz;
#pragma unroll
      for (int ks = 0; ks < 4; ks++) {
        const int pp = ((ks * 4 + q) ^ rx) * 8;
        bf16x8 a0 = *(const bf16x8*)(Qs + (w * 32 + r) * 128 + pp);
        bf16x8 a1 = *(const bf16x8*)(Qs + (w * 32 + 16 + r) * 128 + pp);
#pragma unroll
        for (int ni = 0; ni < 4; ni++) {
          bf16x8 bk = *(const bf16x8*)(Ks + (ni * 16 + r) * 128 + pp);
          s_acc[0][ni] = MFMA16(a0, bk, s_acc[0][ni]);
          s_acc[1][ni] = MFMA16(a1, bk, s_acc[1][ni]);
        }
      }
      // causal mask (only the two diagonal half-tiles need it)
      if ((j == 2 * qt && w < 2) || (j == jmax - 1 && w >= 2)) {
#pragma unroll
        for (int mi = 0; mi < 2; mi++)
#pragma unroll
          for (int ni = 0; ni < 4; ni++)
#pragma unroll
            for (int reg = 0; reg < 4; reg++) {
              const int row_g = qt * 128 + w * 32 + mi * 16 + q * 4 + reg;
              const int col_g = j * 64 + ni * 16 + r;
              if (col_g > row_g) s_acc[mi][ni][reg] = -1e30f;
            }
      }
      // online softmax (rows are wave-exclusive; 16-lane butterfly)
      float alpha[2][4];
#pragma unroll
      for (int mi = 0; mi < 2; mi++)
#pragma unroll
        for (int reg = 0; reg < 4; reg++) {
          float mx = fmaxf(fmaxf(s_acc[mi][0][reg], s_acc[mi][1][reg]),
                           fmaxf(s_acc[mi][2][reg], s_acc[mi][3][reg]));
          mx = fmaxf(mx, __shfl_xor(mx, 1));
          mx = fmaxf(mx, __shfl_xor(mx, 2));
          mx = fmaxf(mx, __shfl_xor(mx, 4));
          mx = fmaxf(mx, __shfl_xor(mx, 8));
          const float mn = fmaxf(m_run[mi][reg], mx);
          alpha[mi][reg] = __expf(m_run[mi][reg] - mn);
          m_run[mi][reg] = mn;
        }
#pragma unroll
      for (int mi = 0; mi < 2; mi++)
#pragma unroll
        for (int ni = 0; ni < 4; ni++)
#pragma unroll
          for (int reg = 0; reg < 4; reg++)
            s_acc[mi][ni][reg] = __expf(s_acc[mi][ni][reg] - m_run[mi][reg]);
#pragma unroll
      for (int mi = 0; mi < 2; mi++)
#pragma unroll
        for (int reg = 0; reg < 4; reg++) {
          float sm = s_acc[mi][0][reg] + s_acc[mi][1][reg] + s_acc[mi][2][reg] + s_acc[mi][3][reg];
          sm += __shfl_xor(sm, 1);
          sm += __shfl_xor(sm, 2);
          sm += __shfl_xor(sm, 4);
          sm += __shfl_xor(sm, 8);
          l_run[mi][reg] = l_run[mi][reg] * alpha[mi][reg] + sm;
        }
#pragma unroll
      for (int mi = 0; mi < 2; mi++)
#pragma unroll
        for (int nd = 0; nd < 8; nd++)
#pragma unroll
          for (int reg = 0; reg < 4; reg++) acc_o[mi][nd][reg] *= alpha[mi][reg];
    }
    __syncthreads();  // b3: all waves done reading Ks; drains V loads
    if (!full_mask) {
      // P (bf16) -> Ps in A-operand-friendly swizzled layout (own rows only)
#pragma unroll
      for (int mi = 0; mi < 2; mi++)
#pragma unroll
        for (int ni = 0; ni < 4; ni++)
#pragma unroll
          for (int reg = 0; reg < 4; reg++) {
            const int row_l = w * 32 + mi * 16 + q * 4 + reg;
            const int col = ni * 16 + r;
            Ks[row_l * 64 + ((col >> 3) ^ (row_l & 7)) * 8 + (col & 7)] =
                f2bf(s_acc[mi][ni][reg]);
          }
      // O += P @ V  (same-wave DS ops are in order; no barrier needed)
#pragma unroll
      for (int ks = 0; ks < 2; ks++) {
        const int pp = ((ks * 4 + q) ^ rx) * 8;
        bf16x8 a0 = *(const bf16x8*)(Ks + (w * 32 + r) * 64 + pp);
        bf16x8 a1 = *(const bf16x8*)(Ks + (w * 32 + 16 + r) * 64 + pp);
#pragma unroll
        for (int nd = 0; nd < 8; nd++) {
          bf16x8 bv = *(const bf16x8*)(Vs + (nd * 16 + r) * 64 + pp);
          acc_o[0][nd] = MFMA16(a0, bv, acc_o[0][nd]);
          acc_o[1][nd] = MFMA16(a1, bv, acc_o[1][nd]);
        }
      }
    }
  }

  // epilogue: O /= l, write bf16 to attn (B*T, 2048) head-major cols
  ushort_t* dst = attn + (b * 2048 + qt * 128) * 2048 + h * 128;
#pragma unroll
  for (int mi = 0; mi < 2; mi++)
#pragma unroll
    for (int reg = 0; reg < 4; reg++) {
      const float inv = 1.0f / l_run[mi][reg];
      const int row_l = w * 32 + mi * 16 + q * 4 + reg;
#pragma unroll
      for (int nd = 0; nd < 8; nd++)
        dst[row_l * 2048 + nd * 16 + r] = f2bf(acc_o[mi][nd][reg] * inv);
    }
}

// ---------------------------------------------------------------- output projection GEMM
__global__ __launch_bounds__(256) void k_gemm_out(const ushort_t* __restrict__ A,
                                                  const ushort_t* __restrict__ Bt,
                                                  float* __restrict__ out) {
  __shared__ __align__(16) ushort_t As[4096];
  __shared__ __align__(16) ushort_t Bs[4096];
  const int t = threadIdx.x;
  const int w = t >> 6;
  const int lane = t & 63;
  const int r = lane & 15;
  const int q = lane >> 4;
  const int m0 = blockIdx.y * 128;
  const int n0 = blockIdx.x * 128;

  const int srow = t >> 2;
  const int gc = (t & 3) ^ ((t >> 3) & 3);
  const int a_g0 = (m0 + srow) * 2048 + gc * 8;
  const int b_g0 = (n0 + srow) * 2048 + gc * 8;
  ushort_t* as_l = As + t * 8;
  ushort_t* bs_l = Bs + t * 8;

  const int pos8 = (q ^ ((r >> 1) & 3)) * 8;
  const int a_off = (w * 32 + r) * 32 + pos8;
  const int b_off = r * 32 + pos8;

  const floatx4 fz = {0.f, 0.f, 0.f, 0.f};
  floatx4 acc[2][8];
#pragma unroll
  for (int i = 0; i < 2; i++)
#pragma unroll
    for (int jj = 0; jj < 8; jj++) acc[i][jj] = fz;

  for (int kt = 0; kt < 2048; kt += 32) {
    gld16(A + a_g0 + kt, as_l);
    gld16(A + a_g0 + 64 * 2048 + kt, as_l + 2048);
    gld16(Bt + b_g0 + kt, bs_l);
    gld16(Bt + b_g0 + 64 * 2048 + kt, bs_l + 2048);
    __syncthreads();
    bf16x8 af0 = *(const bf16x8*)(As + a_off);
    bf16x8 af1 = *(const bf16x8*)(As + a_off + 512);
    bf16x8 bfv[8];
#pragma unroll
    for (int ni = 0; ni < 8; ni++) bfv[ni] = *(const bf16x8*)(Bs + b_off + ni * 512);
#pragma unroll
    for (int ni = 0; ni < 8; ni++) {
      acc[0][ni] = MFMA16(af0, bfv[ni], acc[0][ni]);
      acc[1][ni] = MFMA16(af1, bfv[ni], acc[1][ni]);
    }
    __syncthreads();
  }

#pragma unroll
  for (int mi = 0; mi < 2; mi++)
#pragma unroll
    for (int ni = 0; ni < 8; ni++)
#pragma unroll
      for (int reg = 0; reg < 4; reg++)
        out[(m0 + w * 32 + mi * 16 + q * 4 + reg) * 2048 + n0 + ni * 16 + r] =
            acc[mi][ni][reg];
}

// ---------------------------------------------------------------- launch
extern "C" void kernel_launch(void* const* d_in, const int* in_sizes, int n_in,
                              void* d_out, int out_size, void* d_ws, size_t ws_size,
                              hipStream_t stream) {
  (void)in_sizes; (void)n_in; (void)out_size; (void)ws_size;
  const float* x  = (const float*)d_in[0];
  const float* Wq = (const float*)d_in[1];
  const float* Wk = (const float*)d_in[2];
  const float* Wv = (const float*)d_in[3];
  const float* Wo = (const float*)d_in[4];
  float* out = (float*)d_out;

  char* ws = (char*)d_ws;
  ushort_t* x_bf   = (ushort_t*)(ws);               // 4096x2048        16,777,216 B
  ushort_t* WqkvT  = (ushort_t*)(ws + 16777216);    // 3072x2048        12,582,912 B
  ushort_t* WoT    = (ushort_t*)(ws + 29360128);    // 2048x2048         8,388,608 B
  ushort_t* Qh     = (ushort_t*)(ws + 37748736);    // (B,16,2048,128)  16,777,216 B
  ushort_t* Kh     = (ushort_t*)(ws + 54525952);    // (B,4,2048,128)    4,194,304 B
  ushort_t* Vt     = (ushort_t*)(ws + 58720256);    // (B,4,128,2048)    4,194,304 B
  ushort_t* attn   = (ushort_t*)(ws + 62914560);    // 4096x2048        16,777,216 B

  k_cast_x<<<8192, 256, 0, stream>>>((const floatx4v*)x, (ushortx4*)x_bf);
  k_transpose_cast<<<dim3(32, 32), 256, 0, stream>>>(Wq, WqkvT, 2048);
  k_transpose_cast<<<dim3(8, 32), 256, 0, stream>>>(Wk, WqkvT + 2048 * 2048, 512);
  k_transpose_cast<<<dim3(8, 32), 256, 0, stream>>>(Wv, WqkvT + 2560 * 2048, 512);
  k_transpose_cast<<<dim3(32, 32), 256, 0, stream>>>(Wo, WoT, 2048);
  k_gemm_qkv<<<dim3(24, 32), 256, 0, stream>>>(x_bf, WqkvT, Qh, Kh, Vt);
  k_flash<<<512, 256, 0, stream>>>(Qh, Kh, Vt, attn);
  k_gemm_out<<<dim3(16, 32), 256, 0, stream>>>(attn, WoT, out);
}

// Round 3
// 359.156 us; speedup vs baseline: 1.3456x; 1.0709x over previous
//
#include <hip/hip_runtime.h>

typedef __bf16 bf16x8 __attribute__((ext_vector_type(8)));
typedef float floatx4 __attribute__((ext_vector_type(4)));
typedef unsigned short ushort_t;
typedef ushort_t ushortx4 __attribute__((ext_vector_type(4)));
typedef float floatx4v __attribute__((ext_vector_type(4)));

typedef __attribute__((address_space(1))) void gvoid;
typedef __attribute__((address_space(3))) void svoid;

#define MFMA16(a, b, c) __builtin_amdgcn_mfma_f32_16x16x32_bf16(a, b, c, 0, 0, 0)

__device__ __forceinline__ ushort_t f2bf(float f) {
  unsigned u = __builtin_bit_cast(unsigned, f);
  u += 0x7fffu + ((u >> 16) & 1u);
  return (ushort_t)(u >> 16);
}

__device__ __forceinline__ void gld16(const ushort_t* g, ushort_t* l) {
  __builtin_amdgcn_global_load_lds((gvoid*)(g), (svoid*)(l), 16, 0, 0);
}

// ---------------------------------------------------------------- cast x -> bf16
__global__ __launch_bounds__(256) void k_cast_x(const floatx4v* __restrict__ in,
                                                ushortx4* __restrict__ out) {
  int i = blockIdx.x * 256 + threadIdx.x;
  floatx4v v = in[i];
  ushortx4 o;
  o[0] = f2bf(v[0]); o[1] = f2bf(v[1]); o[2] = f2bf(v[2]); o[3] = f2bf(v[3]);
  out[i] = o;
}

// ---------------------------------------------------------------- all 4 weights: transpose+cast, one launch
__global__ __launch_bounds__(256) void k_prep_w(const float* __restrict__ Wq,
                                                const float* __restrict__ Wk,
                                                const float* __restrict__ Wv,
                                                const float* __restrict__ Wo,
                                                ushort_t* __restrict__ WqkvT,
                                                ushort_t* __restrict__ WoT) {
  __shared__ float tile[64][65];
  const int bx = blockIdx.x;
  const float* in;
  ushort_t* out;
  int N, cx;
  if (bx < 32)      { in = Wq; out = WqkvT;              N = 2048; cx = bx; }
  else if (bx < 40) { in = Wk; out = WqkvT + 2048*2048;  N = 512;  cx = bx - 32; }
  else if (bx < 48) { in = Wv; out = WqkvT + 2560*2048;  N = 512;  cx = bx - 40; }
  else              { in = Wo; out = WoT;                N = 2048; cx = bx - 48; }
  const int c0 = cx * 64;
  const int k0 = blockIdx.y * 64;
  const int tx = threadIdx.x & 63;
  const int ty = threadIdx.x >> 6;
#pragma unroll
  for (int i = 0; i < 16; i++) {
    int row = i * 4 + ty;
    tile[tx][row] = in[(k0 + row) * N + c0 + tx];
  }
  __syncthreads();
#pragma unroll
  for (int i = 0; i < 16; i++) {
    int nr = i * 4 + ty;
    out[(c0 + nr) * 2048 + k0 + tx] = f2bf(tile[nr][tx]);
  }
}

// ---------------------------------------------------------------- fused QKV GEMM + RoPE epilogue
// Double-buffered LDS, ONE barrier per K-step: loads for step it+1 issued right
// after the barrier, in flight across the whole MFMA phase of step it.
__global__ __launch_bounds__(256) void k_gemm_qkv(const ushort_t* __restrict__ A,
                                                  const ushort_t* __restrict__ Bt,
                                                  ushort_t* __restrict__ Qh,
                                                  ushort_t* __restrict__ Kh,
                                                  ushort_t* __restrict__ Vt) {
  __shared__ __align__(16) ushort_t As[2][4096];
  __shared__ __align__(16) ushort_t Bs[2][4096];
  const int t = threadIdx.x;
  const int w = t >> 6;
  const int lane = t & 63;
  const int r = lane & 15;
  const int q = lane >> 4;
  const int m0 = blockIdx.y * 128;
  const int n0 = blockIdx.x * 128;

  const int srow = t >> 2;
  const int gc = (t & 3) ^ ((t >> 3) & 3);          // swizzled global chunk
  const int a_g0 = (m0 + srow) * 2048 + gc * 8;
  const int b_g0 = (n0 + srow) * 2048 + gc * 8;

  const int pos8 = (q ^ ((r >> 1) & 3)) * 8;        // swizzled read position
  const int a_off = (w * 32 + r) * 32 + pos8;
  const int b_off = r * 32 + pos8;

  const floatx4 fz = {0.f, 0.f, 0.f, 0.f};
  floatx4 acc[2][8];
#pragma unroll
  for (int i = 0; i < 2; i++)
#pragma unroll
    for (int jj = 0; jj < 8; jj++) acc[i][jj] = fz;

  // prologue: stage k-step 0 into buf 0
  gld16(A + a_g0, As[0] + t * 8);
  gld16(A + a_g0 + 64 * 2048, As[0] + 2048 + t * 8);
  gld16(Bt + b_g0, Bs[0] + t * 8);
  gld16(Bt + b_g0 + 64 * 2048, Bs[0] + 2048 + t * 8);

  for (int it = 0; it < 64; it++) {
    const int c = it & 1;
    __syncthreads();  // drains buf-c loads (in flight for one full step); buf 1-c free
    if (it < 63) {
      const int kt = (it + 1) * 32;
      gld16(A + a_g0 + kt, As[1 - c] + t * 8);
      gld16(A + a_g0 + 64 * 2048 + kt, As[1 - c] + 2048 + t * 8);
      gld16(Bt + b_g0 + kt, Bs[1 - c] + t * 8);
      gld16(Bt + b_g0 + 64 * 2048 + kt, Bs[1 - c] + 2048 + t * 8);
    }
    bf16x8 af0 = *(const bf16x8*)(As[c] + a_off);
    bf16x8 af1 = *(const bf16x8*)(As[c] + a_off + 512);
    bf16x8 bfv[8];
#pragma unroll
    for (int ni = 0; ni < 8; ni++) bfv[ni] = *(const bf16x8*)(Bs[c] + b_off + ni * 512);
#pragma unroll
    for (int ni = 0; ni < 8; ni++) {
      acc[0][ni] = MFMA16(af0, bfv[ni], acc[0][ni]);
      acc[1][ni] = MFMA16(af1, bfv[ni], acc[1][ni]);
    }
  }

  const int bb = m0 >> 11;                 // batch index (tile never spans b)
  const int trow0 = (m0 & 2047) + w * 32;  // token base for this wave

  if (n0 < 2560) {
    const bool isQ = (n0 < 2048);
    const float scale = isQ ? 0.08838834764831845f : 1.0f;
    ushort_t* dst = isQ ? (Qh + ((bb * 16 + (n0 >> 7)) * 2048) * 128)
                        : (Kh + ((bb * 4 + ((n0 - 2048) >> 7)) * 2048) * 128);
#pragma unroll
    for (int mi = 0; mi < 2; mi++) {
#pragma unroll
      for (int ni = 0; ni < 4; ni++) {
        const int d = ni * 16 + r;
        const float invf = __expf(-0.14391156643f * (float)d);  // 10000^(-d/64)
#pragma unroll
        for (int reg = 0; reg < 4; reg++) {
          const int tt = trow0 + mi * 16 + q * 4 + reg;
          float sn, cs;
          __sincosf((float)tt * invf, &sn, &cs);
          const float lo = acc[mi][ni][reg];
          const float hi = acc[mi][ni + 4][reg];
          dst[tt * 128 + d] = f2bf((lo * cs - hi * sn) * scale);
          dst[tt * 128 + d + 64] = f2bf((hi * cs + lo * sn) * scale);
        }
      }
    }
  } else {
    ushort_t* dst = Vt + ((bb * 4 + ((n0 - 2560) >> 7)) * 128) * 2048;
#pragma unroll
    for (int mi = 0; mi < 2; mi++) {
#pragma unroll
      for (int ni = 0; ni < 8; ni++) {
        const int d = ni * 16 + r;
        const int t0 = trow0 + mi * 16 + q * 4;
        ushortx4 pk;
#pragma unroll
        for (int reg = 0; reg < 4; reg++) pk[reg] = f2bf(acc[mi][ni][reg]);
        *(ushortx4*)(dst + d * 2048 + t0) = pk;
      }
    }
  }
}

// ---------------------------------------------------------------- flash attention (causal, GQA)
// Q fragments in registers; K/V double-buffered in 64 KB LDS. Loads for kv-tile
// j+1 issued at iteration start, in flight across QK+softmax; drained at the
// mid-iteration barrier (which also protects the P->Kc alias). 2 barriers/iter.
__global__ __launch_bounds__(256) void k_flash(const ushort_t* __restrict__ Qh,
                                               const ushort_t* __restrict__ Kh,
                                               const ushort_t* __restrict__ Vt,
                                               ushort_t* __restrict__ attn) {
  __shared__ __align__(16) ushort_t smem[32768];  // K dbuf [0,16K), V dbuf [16K,32K) ushorts

  const int t = threadIdx.x;
  const int w = t >> 6;
  const int lane = t & 63;
  const int r = lane & 15;
  const int q = lane >> 4;
  const int rx = r & 7;

  // work-balanced remap: block i and i+256 share a CU; qt(i)+qt(i+256)=15
  const int kk = blockIdx.x & 255;
  const int hi2 = blockIdx.x >> 8;
  const int bh = kk >> 3;
  const int ss = kk & 7;
  const int qt = hi2 ? (15 - ss) : ss;

  const int b = bh >> 4;
  const int h = bh & 15;
  const int hkv = h >> 2;

  const ushort_t* Qg = Qh + (bh * 2048 + qt * 128) * 128;
  const ushort_t* Kg = Kh + ((b * 4 + hkv) * 2048) * 128;
  const ushort_t* Vg = Vt + ((b * 4 + hkv) * 128) * 2048;

  // ---- stage Q through LDS (reusing K dbuf region), hoist fragments to regs
  {
    const int row = t >> 4;
    const int gcq = (t & 15) ^ ((t >> 4) & 7);
#pragma unroll
    for (int i = 0; i < 8; i++)
      gld16(Qg + (i * 16 + row) * 128 + gcq * 8, smem + i * 2048 + t * 8);
  }
  __syncthreads();
  bf16x8 aq0[4], aq1[4];
#pragma unroll
  for (int ks = 0; ks < 4; ks++) {
    const int pp = ((ks * 4 + q) ^ rx) * 8;
    aq0[ks] = *(const bf16x8*)(smem + (w * 32 + r) * 128 + pp);
    aq1[ks] = *(const bf16x8*)(smem + (w * 32 + 16 + r) * 128 + pp);
  }
  __syncthreads();  // everyone done reading Q before K0/V0 overwrite the region

  const int jmax = 2 * qt + 2;
  const int krow = t >> 4;
  const int gck = (t & 15) ^ ((t >> 4) & 7);
  const int vrow = t >> 3;
  const int gcv = (t & 7) ^ ((t >> 3) & 7);

  // issue K0/V0 into buf 0
#pragma unroll
  for (int i = 0; i < 4; i++)
    gld16(Kg + (i * 16 + krow) * 128 + gck * 8, smem + i * 2048 + t * 8);
#pragma unroll
  for (int i = 0; i < 4; i++)
    gld16(Vg + (i * 32 + vrow) * 2048 + gcv * 8, smem + 16384 + i * 2048 + t * 8);

  const floatx4 fz = {0.f, 0.f, 0.f, 0.f};
  floatx4 acc_o[2][8];
#pragma unroll
  for (int i = 0; i < 2; i++)
#pragma unroll
    for (int jj = 0; jj < 8; jj++) acc_o[i][jj] = fz;
  float m_run[2][4], l_run[2][4];
#pragma unroll
  for (int i = 0; i < 2; i++)
#pragma unroll
    for (int jj = 0; jj < 4; jj++) { m_run[i][jj] = -1e30f; l_run[i][jj] = 0.f; }

  floatx4 s_acc[2][4];

  for (int j = 0; j < jmax; j++) {
    const int c = j & 1;
    ushort_t* Kc = smem + c * 8192;
    ushort_t* Vc = smem + 16384 + c * 8192;
    __syncthreads();  // b1: buf 1-c free (PV_{j-1} done); vmcnt already ~0 from prev b2
    if (j + 1 < jmax) {
      ushort_t* Kn = smem + (1 - c) * 8192;
      ushort_t* Vn = smem + 16384 + (1 - c) * 8192;
#pragma unroll
      for (int i = 0; i < 4; i++)
        gld16(Kg + ((j + 1) * 64 + i * 16 + krow) * 128 + gck * 8, Kn + i * 2048 + t * 8);
#pragma unroll
      for (int i = 0; i < 4; i++)
        gld16(Vg + (i * 32 + vrow) * 2048 + (j + 1) * 64 + gcv * 8, Vn + i * 2048 + t * 8);
    }

    const bool full_mask = (j == jmax - 1) && (w < 2);  // upper diag half-tile: all masked
    if (!full_mask) {
#pragma unroll
      for (int mi = 0; mi < 2; mi++)
#pragma unroll
        for (int ni = 0; ni < 4; ni++) s_acc[mi][ni] = fz;
#pragma unroll
      for (int ks = 0; ks < 4; ks++) {
        const int pp = ((ks * 4 + q) ^ rx) * 8;
#pragma unroll
        for (int ni = 0; ni < 4; ni++) {
          bf16x8 bk = *(const bf16x8*)(Kc + (ni * 16 + r) * 128 + pp);
          s_acc[0][ni] = MFMA16(aq0[ks], bk, s_acc[0][ni]);
          s_acc[1][ni] = MFMA16(aq1[ks], bk, s_acc[1][ni]);
        }
      }
      // causal mask (only the two diagonal half-tiles need it)
      if ((j == 2 * qt && w < 2) || (j == jmax - 1 && w >= 2)) {
#pragma unroll
        for (int mi = 0; mi < 2; mi++)
#pragma unroll
          for (int ni = 0; ni < 4; ni++)
#pragma unroll
            for (int reg = 0; reg < 4; reg++) {
              const int row_g = qt * 128 + w * 32 + mi * 16 + q * 4 + reg;
              const int col_g = j * 64 + ni * 16 + r;
              if (col_g > row_g) s_acc[mi][ni][reg] = -1e30f;
            }
      }
      // online softmax (rows are wave-exclusive; 16-lane butterfly)
      float alpha[2][4];
#pragma unroll
      for (int mi = 0; mi < 2; mi++)
#pragma unroll
        for (int reg = 0; reg < 4; reg++) {
          float mx = fmaxf(fmaxf(s_acc[mi][0][reg], s_acc[mi][1][reg]),
                           fmaxf(s_acc[mi][2][reg], s_acc[mi][3][reg]));
          mx = fmaxf(mx, __shfl_xor(mx, 1));
          mx = fmaxf(mx, __shfl_xor(mx, 2));
          mx = fmaxf(mx, __shfl_xor(mx, 4));
          mx = fmaxf(mx, __shfl_xor(mx, 8));
          const float mn = fmaxf(m_run[mi][reg], mx);
          alpha[mi][reg] = __expf(m_run[mi][reg] - mn);
          m_run[mi][reg] = mn;
        }
#pragma unroll
      for (int mi = 0; mi < 2; mi++)
#pragma unroll
        for (int ni = 0; ni < 4; ni++)
#pragma unroll
          for (int reg = 0; reg < 4; reg++)
            s_acc[mi][ni][reg] = __expf(s_acc[mi][ni][reg] - m_run[mi][reg]);
#pragma unroll
      for (int mi = 0; mi < 2; mi++)
#pragma unroll
        for (int reg = 0; reg < 4; reg++) {
          float sm = s_acc[mi][0][reg] + s_acc[mi][1][reg] + s_acc[mi][2][reg] + s_acc[mi][3][reg];
          sm += __shfl_xor(sm, 1);
          sm += __shfl_xor(sm, 2);
          sm += __shfl_xor(sm, 4);
          sm += __shfl_xor(sm, 8);
          l_run[mi][reg] = l_run[mi][reg] * alpha[mi][reg] + sm;
        }
#pragma unroll
      for (int mi = 0; mi < 2; mi++)
#pragma unroll
        for (int nd = 0; nd < 8; nd++)
#pragma unroll
          for (int reg = 0; reg < 4; reg++) acc_o[mi][nd][reg] *= alpha[mi][reg];
    }
    __syncthreads();  // b2: all waves done reading Kc; drains j+1 loads (flew QK+softmax)
    if (!full_mask) {
      // P (bf16) -> Kc alias, A-operand swizzled layout (own rows only)
#pragma unroll
      for (int mi = 0; mi < 2; mi++)
#pragma unroll
        for (int ni = 0; ni < 4; ni++)
#pragma unroll
          for (int reg = 0; reg < 4; reg++) {
            const int row_l = w * 32 + mi * 16 + q * 4 + reg;
            const int col = ni * 16 + r;
            Kc[row_l * 64 + ((col >> 3) ^ (row_l & 7)) * 8 + (col & 7)] =
                f2bf(s_acc[mi][ni][reg]);
          }
      // O += P @ V  (same-wave DS ops are in order; no barrier needed)
#pragma unroll
      for (int ks = 0; ks < 2; ks++) {
        const int pp = ((ks * 4 + q) ^ rx) * 8;
        bf16x8 a0 = *(const bf16x8*)(Kc + (w * 32 + r) * 64 + pp);
        bf16x8 a1 = *(const bf16x8*)(Kc + (w * 32 + 16 + r) * 64 + pp);
#pragma unroll
        for (int nd = 0; nd < 8; nd++) {
          bf16x8 bv = *(const bf16x8*)(Vc + (nd * 16 + r) * 64 + pp);
          acc_o[0][nd] = MFMA16(a0, bv, acc_o[0][nd]);
          acc_o[1][nd] = MFMA16(a1, bv, acc_o[1][nd]);
        }
      }
    }
  }

  // epilogue: O /= l, write bf16 to attn (B*T, 2048) head-major cols
  ushort_t* dst = attn + (b * 2048 + qt * 128) * 2048 + h * 128;
#pragma unroll
  for (int mi = 0; mi < 2; mi++)
#pragma unroll
    for (int reg = 0; reg < 4; reg++) {
      const float inv = 1.0f / l_run[mi][reg];
      const int row_l = w * 32 + mi * 16 + q * 4 + reg;
#pragma unroll
      for (int nd = 0; nd < 8; nd++)
        dst[row_l * 2048 + nd * 16 + r] = f2bf(acc_o[mi][nd][reg] * inv);
    }
}

// ---------------------------------------------------------------- output projection GEMM (dbuf, 1 barrier/step)
__global__ __launch_bounds__(256) void k_gemm_out(const ushort_t* __restrict__ A,
                                                  const ushort_t* __restrict__ Bt,
                                                  float* __restrict__ out) {
  __shared__ __align__(16) ushort_t As[2][4096];
  __shared__ __align__(16) ushort_t Bs[2][4096];
  const int t = threadIdx.x;
  const int w = t >> 6;
  const int lane = t & 63;
  const int r = lane & 15;
  const int q = lane >> 4;
  const int m0 = blockIdx.y * 128;
  const int n0 = blockIdx.x * 128;

  const int srow = t >> 2;
  const int gc = (t & 3) ^ ((t >> 3) & 3);
  const int a_g0 = (m0 + srow) * 2048 + gc * 8;
  const int b_g0 = (n0 + srow) * 2048 + gc * 8;

  const int pos8 = (q ^ ((r >> 1) & 3)) * 8;
  const int a_off = (w * 32 + r) * 32 + pos8;
  const int b_off = r * 32 + pos8;

  const floatx4 fz = {0.f, 0.f, 0.f, 0.f};
  floatx4 acc[2][8];
#pragma unroll
  for (int i = 0; i < 2; i++)
#pragma unroll
    for (int jj = 0; jj < 8; jj++) acc[i][jj] = fz;

  gld16(A + a_g0, As[0] + t * 8);
  gld16(A + a_g0 + 64 * 2048, As[0] + 2048 + t * 8);
  gld16(Bt + b_g0, Bs[0] + t * 8);
  gld16(Bt + b_g0 + 64 * 2048, Bs[0] + 2048 + t * 8);

  for (int it = 0; it < 64; it++) {
    const int c = it & 1;
    __syncthreads();
    if (it < 63) {
      const int kt = (it + 1) * 32;
      gld16(A + a_g0 + kt, As[1 - c] + t * 8);
      gld16(A + a_g0 + 64 * 2048 + kt, As[1 - c] + 2048 + t * 8);
      gld16(Bt + b_g0 + kt, Bs[1 - c] + t * 8);
      gld16(Bt + b_g0 + 64 * 2048 + kt, Bs[1 - c] + 2048 + t * 8);
    }
    bf16x8 af0 = *(const bf16x8*)(As[c] + a_off);
    bf16x8 af1 = *(const bf16x8*)(As[c] + a_off + 512);
    bf16x8 bfv[8];
#pragma unroll
    for (int ni = 0; ni < 8; ni++) bfv[ni] = *(const bf16x8*)(Bs[c] + b_off + ni * 512);
#pragma unroll
    for (int ni = 0; ni < 8; ni++) {
      acc[0][ni] = MFMA16(af0, bfv[ni], acc[0][ni]);
      acc[1][ni] = MFMA16(af1, bfv[ni], acc[1][ni]);
    }
  }

#pragma unroll
  for (int mi = 0; mi < 2; mi++)
#pragma unroll
    for (int ni = 0; ni < 8; ni++)
#pragma unroll
      for (int reg = 0; reg < 4; reg++)
        out[(m0 + w * 32 + mi * 16 + q * 4 + reg) * 2048 + n0 + ni * 16 + r] =
            acc[mi][ni][reg];
}

// ---------------------------------------------------------------- launch
extern "C" void kernel_launch(void* const* d_in, const int* in_sizes, int n_in,
                              void* d_out, int out_size, void* d_ws, size_t ws_size,
                              hipStream_t stream) {
  (void)in_sizes; (void)n_in; (void)out_size; (void)ws_size;
  const float* x  = (const float*)d_in[0];
  const float* Wq = (const float*)d_in[1];
  const float* Wk = (const float*)d_in[2];
  const float* Wv = (const float*)d_in[3];
  const float* Wo = (const float*)d_in[4];
  float* out = (float*)d_out;

  char* ws = (char*)d_ws;
  ushort_t* x_bf   = (ushort_t*)(ws);               // 4096x2048        16,777,216 B
  ushort_t* WqkvT  = (ushort_t*)(ws + 16777216);    // 3072x2048        12,582,912 B
  ushort_t* WoT    = (ushort_t*)(ws + 29360128);    // 2048x2048         8,388,608 B
  ushort_t* Qh     = (ushort_t*)(ws + 37748736);    // (B,16,2048,128)  16,777,216 B
  ushort_t* Kh     = (ushort_t*)(ws + 54525952);    // (B,4,2048,128)    4,194,304 B
  ushort_t* Vt     = (ushort_t*)(ws + 58720256);    // (B,4,128,2048)    4,194,304 B
  ushort_t* attn   = (ushort_t*)(ws + 62914560);    // 4096x2048        16,777,216 B

  k_cast_x<<<8192, 256, 0, stream>>>((const floatx4v*)x, (ushortx4*)x_bf);
  k_prep_w<<<dim3(80, 32), 256, 0, stream>>>(Wq, Wk, Wv, Wo, WqkvT, WoT);
  k_gemm_qkv<<<dim3(24, 32), 256, 0, stream>>>(x_bf, WqkvT, Qh, Kh, Vt);
  k_flash<<<512, 256, 0, stream>>>(Qh, Kh, Vt, attn);
  k_gemm_out<<<dim3(16, 32), 256, 0, stream>>>(attn, WoT, out);
}